// Round 7
// baseline (2300.492 us; speedup 1.0000x reference)
//
#include <hip/hip_runtime.h>
#include <hip/hip_bf16.h>
#include <math.h>

#define VOCABN 256
#define EMBN   384
#define DM     512
#define DI     1024
#define DSTATE 16
#define DCONVN 4
#define DTRANK 32
#define NLAYER 8
#define BBATCH 2
#define LSEQ   2048
#define MROWS  (BBATCH*LSEQ)   // 4096
#define SCHUNK 64
#define NCHUNK (LSEQ/SCHUNK)   // 32

typedef short s8v  __attribute__((ext_vector_type(8)));
typedef float f32x4 __attribute__((ext_vector_type(4)));

// ---------------- bf16 split/pack helpers ----------------
__device__ __forceinline__ ushort f2bf(float f) {
    uint u = __float_as_uint(f);
    return (ushort)((u + 0x7fffu + ((u >> 16) & 1u)) >> 16);
}
__device__ __forceinline__ float bf2f(ushort h) {
    return __uint_as_float((uint)h << 16);
}
// packed element: hi bf16 in high 16 bits, lo bf16 (residual) in low 16 bits
__device__ __forceinline__ uint packbf(float f) {
    ushort h = f2bf(f);
    ushort l = f2bf(f - bf2f(h));
    return ((uint)h << 16) | (uint)l;
}
__device__ __forceinline__ void unp4(uint4 p, ushort* hdst, ushort* ldst) {
    ushort4 h, l;
    h.x = (ushort)(p.x >> 16); l.x = (ushort)(p.x & 0xffffu);
    h.y = (ushort)(p.y >> 16); l.y = (ushort)(p.y & 0xffffu);
    h.z = (ushort)(p.z >> 16); l.z = (ushort)(p.z & 0xffffu);
    h.w = (ushort)(p.w >> 16); l.w = (ushort)(p.w & 0xffffu);
    *(ushort4*)hdst = h; *(ushort4*)ldst = l;
}

// ---------------- pack kernels ----------------
__global__ void pack4_kernel(const float* __restrict__ a, int na,
                             const float* __restrict__ b, int nb,
                             const float* __restrict__ c, int nc,
                             const float* __restrict__ d, int nd,
                             uint* __restrict__ pa, uint* __restrict__ pb,
                             uint* __restrict__ pc, uint* __restrict__ pd) {
    int i = blockIdx.x * 256 + threadIdx.x;
    if (i < na) pa[i] = packbf(a[i]);
    else if (i < na + nb) pb[i - na] = packbf(b[i - na]);
    else if (i < na + nb + nc) pc[i - na - nb] = packbf(c[i - na - nb]);
    else if (i < na + nb + nc + nd) pd[i - na - nb - nc] = packbf(d[i - na - nb - nc]);
}

// conv weights: w[co][ci][k] fp32 -> pw[k][co][ci] packed
template<int CI, int CK>
__global__ void pack_convw_kernel(const float* __restrict__ w, uint* __restrict__ pw) {
    int idx = blockIdx.x * 256 + threadIdx.x;
    if (idx >= 512 * CI * CK) return;
    int k  = idx % CK;
    int ci = (idx / CK) % CI;
    int co = idx / (CK * CI);
    pw[((size_t)(k * 512) + co) * CI + ci] = packbf(w[idx]);
}

// ---------------- embedding gather -> packed ----------------
__global__ void embed_kernel(const int* __restrict__ tok, const float* __restrict__ emb,
                             uint* __restrict__ px0) {
    int idx = blockIdx.x * 256 + threadIdx.x;   // over MROWS*EMBN
    int c = idx % EMBN;
    int t = idx / EMBN;
    px0[idx] = packbf(emb[tok[t] * EMBN + c]);
}

__device__ __forceinline__ float gelu_exact(float x) {
    return 0.5f * x * (1.f + erff(x * 0.70710678118654752f));
}

// ---------------- conv as implicit-GEMM MFMA (bf16x3) ----------------
template<int CI, int CK, int PAD>
__global__ __launch_bounds__(256) void conv_mfma_kernel(
    const uint* __restrict__ PA, const uint* __restrict__ PW,
    const float* __restrict__ bias, float* __restrict__ out)
{
    constexpr int ROWS = 128 + CK - 1;
    const int t0  = blockIdx.x * 128;
    const int co0 = blockIdx.y * 32;
    const int tid = threadIdx.x;
    const int wid = tid >> 6, lane = tid & 63;
    const int rb = wid * 32;
    const int lr = lane & 15, lk = (lane >> 4) * 8;
    const int bstart = (t0 / LSEQ) * LSEQ;

    __shared__ alignas(16) ushort Ah[ROWS][40], Al[ROWS][40];
    __shared__ alignas(16) ushort Bh[CK][32][40], Bl[CK][32][40];

    f32x4 acc[2][2];
#pragma unroll
    for (int m = 0; m < 2; m++)
#pragma unroll
        for (int n = 0; n < 2; n++) acc[m][n] = (f32x4){0.f, 0.f, 0.f, 0.f};

    for (int ci0 = 0; ci0 < CI; ci0 += 32) {
        __syncthreads();
        for (int idx = tid; idx < ROWS * 8; idx += 256) {
            int r = idx >> 3, c4 = (idx & 7) * 4;
            int g = t0 - PAD + r;
            uint4 v = make_uint4(0u, 0u, 0u, 0u);
            if (g >= bstart && g < bstart + LSEQ)
                v = *(const uint4*)&PA[(size_t)g * CI + ci0 + c4];
            unp4(v, &Ah[r][c4], &Al[r][c4]);
        }
        for (int idx = tid; idx < CK * 32 * 8; idx += 256) {
            int k = idx >> 8;
            int r = (idx >> 3) & 31;
            int c4 = (idx & 7) * 4;
            uint4 v = *(const uint4*)&PW[((size_t)(k * 512) + co0 + r) * CI + ci0 + c4];
            unp4(v, &Bh[k][r][c4], &Bl[k][r][c4]);
        }
        __syncthreads();

#pragma unroll
        for (int k = 0; k < CK; k++) {
            s8v ah[2], al[2], bh[2], bl[2];
#pragma unroll
            for (int m = 0; m < 2; m++) {
                ah[m] = *(const s8v*)&Ah[rb + m * 16 + lr + k][lk];
                al[m] = *(const s8v*)&Al[rb + m * 16 + lr + k][lk];
            }
#pragma unroll
            for (int n = 0; n < 2; n++) {
                bh[n] = *(const s8v*)&Bh[k][n * 16 + lr][lk];
                bl[n] = *(const s8v*)&Bl[k][n * 16 + lr][lk];
            }
#pragma unroll
            for (int m = 0; m < 2; m++)
#pragma unroll
                for (int n = 0; n < 2; n++) {
                    acc[m][n] = __builtin_amdgcn_mfma_f32_16x16x32_bf16(ah[m], bh[n], acc[m][n], 0, 0, 0);
                    acc[m][n] = __builtin_amdgcn_mfma_f32_16x16x32_bf16(ah[m], bl[n], acc[m][n], 0, 0, 0);
                    acc[m][n] = __builtin_amdgcn_mfma_f32_16x16x32_bf16(al[m], bh[n], acc[m][n], 0, 0, 0);
                }
        }
    }

#pragma unroll
    for (int m = 0; m < 2; m++)
#pragma unroll
        for (int n = 0; n < 2; n++) {
            int gcol = co0 + n * 16 + lr;
            float bv = bias[gcol];
#pragma unroll
            for (int r = 0; r < 4; r++) {
                int grow = t0 + rb + m * 16 + (lane >> 4) * 4 + r;
                out[(size_t)grow * 512 + gcol] = gelu_exact(acc[m][n][r] + bv);
            }
        }
}

// ---------------- layernorm over 512, optional +pos_emb; packed or fp32 out ----------------
template<bool ADDPOS, bool PACK>
__global__ __launch_bounds__(256) void ln_kernel(
    const float* __restrict__ in, const float* __restrict__ g, const float* __restrict__ bb,
    const float* __restrict__ pos, float* __restrict__ out, uint* __restrict__ pout)
{
    int row  = blockIdx.x * 4 + (threadIdx.x >> 6);
    int lane = threadIdx.x & 63;
    const float* xr = in + (size_t)row * DM;
    float v[8];
    float s = 0.f;
#pragma unroll
    for (int i = 0; i < 8; i++) { v[i] = xr[lane + i * 64]; s += v[i]; }
#pragma unroll
    for (int o = 32; o >= 1; o >>= 1) s += __shfl_xor(s, o);
    float mu = s * (1.f / 512.f);
    float var = 0.f;
#pragma unroll
    for (int i = 0; i < 8; i++) { float d = v[i] - mu; var = fmaf(d, d, var); }
#pragma unroll
    for (int o = 32; o >= 1; o >>= 1) var += __shfl_xor(var, o);
    var *= (1.f / 512.f);
    float rstd = rsqrtf(var + 1e-5f);
    int t = row & (LSEQ - 1);
#pragma unroll
    for (int i = 0; i < 8; i++) {
        int c = lane + i * 64;
        float o = (v[i] - mu) * rstd * g[c] + bb[c];
        if (ADDPOS) o += pos[t * DM + c];
        if (PACK) pout[(size_t)row * DM + c] = packbf(o);
        else      out [(size_t)row * DM + c] = o;
    }
}

// ---------------- packed-bf16x3 MFMA GEMM ----------------
// EPI: 0 = fp32 C only; 2 = fp32 C + packed PC; 3 = bias+softplus, fp32 C only.
template<int BN, int EPI>
__global__ __launch_bounds__(256) void gemm_mfma_p(
    const uint* __restrict__ PA, int lda,
    const uint* __restrict__ PW,
    const float* __restrict__ bias,
    float* __restrict__ C, uint* __restrict__ PC, int N, int K)
{
    constexpr int MR = (BN == 128) ? 4 : 2;
    constexpr int NR = 4;
    const int m0 = blockIdx.x * 128;
    const int n0 = blockIdx.y * BN;
    const int tid = threadIdx.x;
    const int wid = tid >> 6;
    const int lane = tid & 63;
    const int rb = (BN == 128) ? (wid >> 1) * 64 : wid * 32;
    const int cb = (BN == 128) ? (wid & 1) * 64 : 0;
    const int lr = lane & 15;
    const int lk = (lane >> 4) * 8;

    __shared__ alignas(16) ushort Ah[128][40], Al[128][40];
    __shared__ alignas(16) ushort Bh[BN][40],  Bl[BN][40];

    f32x4 acc[MR][NR];
#pragma unroll
    for (int m = 0; m < MR; m++)
#pragma unroll
        for (int n = 0; n < NR; n++) acc[m][n] = (f32x4){0.f, 0.f, 0.f, 0.f};

    const int srow = tid >> 3;        // 0..31
    const int scol = (tid & 7) * 4;   // 0,4,...,28

    for (int k0 = 0; k0 < K; k0 += 32) {
        uint4 av[4], wv[BN / 32];
#pragma unroll
        for (int i = 0; i < 4; i++)
            av[i] = *(const uint4*)&PA[(size_t)(m0 + srow + 32 * i) * lda + k0 + scol];
#pragma unroll
        for (int i = 0; i < BN / 32; i++)
            wv[i] = *(const uint4*)&PW[(size_t)(n0 + srow + 32 * i) * K + k0 + scol];

        __syncthreads();
#pragma unroll
        for (int i = 0; i < 4; i++)
            unp4(av[i], &Ah[srow + 32 * i][scol], &Al[srow + 32 * i][scol]);
#pragma unroll
        for (int i = 0; i < BN / 32; i++)
            unp4(wv[i], &Bh[srow + 32 * i][scol], &Bl[srow + 32 * i][scol]);
        __syncthreads();

        s8v ah[MR], al[MR], bh[NR], bl[NR];
#pragma unroll
        for (int m = 0; m < MR; m++) {
            ah[m] = *(const s8v*)&Ah[rb + m * 16 + lr][lk];
            al[m] = *(const s8v*)&Al[rb + m * 16 + lr][lk];
        }
#pragma unroll
        for (int n = 0; n < NR; n++) {
            bh[n] = *(const s8v*)&Bh[cb + n * 16 + lr][lk];
            bl[n] = *(const s8v*)&Bl[cb + n * 16 + lr][lk];
        }
#pragma unroll
        for (int m = 0; m < MR; m++)
#pragma unroll
            for (int n = 0; n < NR; n++) {
                acc[m][n] = __builtin_amdgcn_mfma_f32_16x16x32_bf16(ah[m], bh[n], acc[m][n], 0, 0, 0);
                acc[m][n] = __builtin_amdgcn_mfma_f32_16x16x32_bf16(ah[m], bl[n], acc[m][n], 0, 0, 0);
                acc[m][n] = __builtin_amdgcn_mfma_f32_16x16x32_bf16(al[m], bh[n], acc[m][n], 0, 0, 0);
            }
    }

#pragma unroll
    for (int m = 0; m < MR; m++)
#pragma unroll
        for (int n = 0; n < NR; n++) {
#pragma unroll
            for (int r = 0; r < 4; r++) {
                int grow = m0 + rb + m * 16 + (lane >> 4) * 4 + r;
                int gcol = n0 + cb + n * 16 + lr;
                float v = acc[m][n][r];
                if (EPI == 3) {
                    v += bias[gcol];
                    v = fmaxf(v, 0.f) + log1pf(expf(-fabsf(v)));   // softplus, stable
                }
                C[(size_t)grow * N + gcol] = v;
                if (EPI == 2) PC[(size_t)grow * N + gcol] = packbf(v);
            }
        }
}

// ---------------- depthwise causal conv(4) + silu; fp32 + packed out ----------------
__global__ void dwconv_silu_kernel(const float* __restrict__ xz, const float* __restrict__ cw,
                                   const float* __restrict__ cb, float* __restrict__ xc,
                                   uint* __restrict__ pxc) {
    int idx = blockIdx.x * 256 + threadIdx.x;   // over MROWS*DI
    int d = idx & (DI - 1);
    int r = idx >> 10;                          // row = b*L + t
    int tl = r & (LSEQ - 1);
    float acc = cb[d];
#pragma unroll
    for (int k = 0; k < DCONVN; k++) {
        int ts = tl - 3 + k;
        if (ts >= 0) acc = fmaf(xz[(size_t)(r - 3 + k) * (2 * DI) + d], cw[d * DCONVN + k], acc);
    }
    float sig = 1.f / (1.f + expf(-acc));
    float v = acc * sig;
    xc[idx] = v;
    pxc[idx] = packbf(v);
}

// ---------------- chunked selective scan, 4-states-per-thread, LDS-staged ----------------
// thread = (d, sg): sg = tid&3 owns states s = sg*4..sg*4+3 in registers.
// block = 256 thr (64 d x 4 sg). grid = 16 dq x NCHUNK x B. Block tile = 64 t x 64 d.
__global__ __launch_bounds__(256) void scan_local_kernel(
    const float* __restrict__ dt, const float* __restrict__ xc,
    const float* __restrict__ dbc, const float* __restrict__ A_log,
    float* __restrict__ S, float* __restrict__ P)
{
    const int sg = threadIdx.x & 3;
    const int dl = threadIdx.x >> 2;           // 0..63
    const int dq = blockIdx.x & 15;
    const int c  = (blockIdx.x >> 4) & (NCHUNK - 1);
    const int b  = blockIdx.x >> 9;
    const int d0 = dq * 64;
    const int d  = d0 + dl;
    const int rowbase = b * LSEQ + c * SCHUNK;

    __shared__ float dtl[SCHUNK][68];          // [t][d], pad 68 -> conflict-free b32 reads
    __shared__ float xcl[SCHUNK][68];
    __shared__ float bl [SCHUNK][16];          // B part of dbc

    for (int i = threadIdx.x; i < SCHUNK * 16; i += 256) {
        int t = i >> 4, c4 = (i & 15) * 4;
        *(float4*)&dtl[t][c4] = *(const float4*)&dt[(size_t)(rowbase + t) * DI + d0 + c4];
        *(float4*)&xcl[t][c4] = *(const float4*)&xc[(size_t)(rowbase + t) * DI + d0 + c4];
    }
    for (int i = threadIdx.x; i < SCHUNK * 4; i += 256) {
        int t = i >> 2, c4 = (i & 3) * 4;
        *(float4*)&bl[t][c4] = *(const float4*)&dbc[(size_t)(rowbase + t) * 64 + DTRANK + c4];
    }

    float4 alog = *(const float4*)&A_log[d * DSTATE + sg * 4];
    float Av[4]; // -exp(A_log) * log2(e), pre-folded for exp2f
    Av[0] = -expf(alog.x) * 1.44269504f;
    Av[1] = -expf(alog.y) * 1.44269504f;
    Av[2] = -expf(alog.z) * 1.44269504f;
    Av[3] = -expf(alog.w) * 1.44269504f;

    float h[4] = {0.f, 0.f, 0.f, 0.f};
    float sumdt = 0.f;
    __syncthreads();

#pragma unroll 4
    for (int t = 0; t < SCHUNK; t++) {
        float dtv = dtl[t][dl];
        float xcv = xcl[t][dl];
        float4 Bv = *(const float4*)&bl[t][sg * 4];
        float dx = dtv * xcv;
        h[0] = fmaf(exp2f(dtv * Av[0]), h[0], dx * Bv.x);
        h[1] = fmaf(exp2f(dtv * Av[1]), h[1], dx * Bv.y);
        h[2] = fmaf(exp2f(dtv * Av[2]), h[2], dx * Bv.z);
        h[3] = fmaf(exp2f(dtv * Av[3]), h[3], dx * Bv.w);
        sumdt += dtv;
    }
    size_t off = ((size_t)(b * NCHUNK + c) * DI + d) * DSTATE + sg * 4;
    *(float4*)&S[off] = make_float4(h[0], h[1], h[2], h[3]);
    *(float4*)&P[off] = make_float4(exp2f(Av[0] * sumdt), exp2f(Av[1] * sumdt),
                                    exp2f(Av[2] * sumdt), exp2f(Av[3] * sumdt));
}

__global__ __launch_bounds__(256) void scan_combine_kernel(
    const float* __restrict__ S, const float* __restrict__ P, float* __restrict__ H)
{
    int idx = blockIdx.x * 256 + threadIdx.x;    // over B*DI*DSTATE = 32768
    int b = idx >> 14;
    int rem = idx & 16383;                        // d*16+s
    float h = 0.f;
#pragma unroll
    for (int c = 0; c < NCHUNK; c++) {
        size_t off = ((size_t)(b * NCHUNK + c) * DI) * DSTATE + rem;
        H[off] = h;
        h = fmaf(P[off], h, S[off]);
    }
}

__global__ __launch_bounds__(256) void scan_out_kernel(
    const float* __restrict__ dt, const float* __restrict__ xc,
    const float* __restrict__ dbc, const float* __restrict__ xz,
    const float* __restrict__ A_log, const float* __restrict__ Dp,
    const float* __restrict__ H, uint* __restrict__ py)
{
    const int sg = threadIdx.x & 3;
    const int dl = threadIdx.x >> 2;
    const int dq = blockIdx.x & 15;
    const int c  = (blockIdx.x >> 4) & (NCHUNK - 1);
    const int b  = blockIdx.x >> 9;
    const int d0 = dq * 64;
    const int d  = d0 + dl;
    const int rowbase = b * LSEQ + c * SCHUNK;

    __shared__ float dtl[SCHUNK][68];
    __shared__ float xcl[SCHUNK][68];
    __shared__ float bcl[SCHUNK][32];          // B and C parts of dbc

    for (int i = threadIdx.x; i < SCHUNK * 16; i += 256) {
        int t = i >> 4, c4 = (i & 15) * 4;
        *(float4*)&dtl[t][c4] = *(const float4*)&dt[(size_t)(rowbase + t) * DI + d0 + c4];
        *(float4*)&xcl[t][c4] = *(const float4*)&xc[(size_t)(rowbase + t) * DI + d0 + c4];
    }
    for (int i = threadIdx.x; i < SCHUNK * 8; i += 256) {
        int t = i >> 3, c4 = (i & 7) * 4;
        *(float4*)&bcl[t][c4] = *(const float4*)&dbc[(size_t)(rowbase + t) * 64 + DTRANK + c4];
    }

    float4 alog = *(const float4*)&A_log[d * DSTATE + sg * 4];
    float Av[4];
    Av[0] = -expf(alog.x) * 1.44269504f;
    Av[1] = -expf(alog.y) * 1.44269504f;
    Av[2] = -expf(alog.z) * 1.44269504f;
    Av[3] = -expf(alog.w) * 1.44269504f;
    float Dval = Dp[d];

    float4 hv = *(const float4*)&H[((size_t)(b * NCHUNK + c) * DI + d) * DSTATE + sg * 4];
    float h[4] = {hv.x, hv.y, hv.z, hv.w};
    __syncthreads();

#pragma unroll 4
    for (int t = 0; t < SCHUNK; t++) {
        float dtv = dtl[t][dl];
        float xcv = xcl[t][dl];
        float4 Bv = *(const float4*)&bcl[t][sg * 4];
        float4 Cv = *(const float4*)&bcl[t][16 + sg * 4];
        float dx = dtv * xcv;
        h[0] = fmaf(exp2f(dtv * Av[0]), h[0], dx * Bv.x);
        h[1] = fmaf(exp2f(dtv * Av[1]), h[1], dx * Bv.y);
        h[2] = fmaf(exp2f(dtv * Av[2]), h[2], dx * Bv.z);
        h[3] = fmaf(exp2f(dtv * Av[3]), h[3], dx * Bv.w);
        float p = h[0] * Cv.x;
        p = fmaf(h[1], Cv.y, p);
        p = fmaf(h[2], Cv.z, p);
        p = fmaf(h[3], Cv.w, p);
        p += __shfl_xor(p, 1);
        p += __shfl_xor(p, 2);
        if (sg == 0) {
            float zv = xz[(size_t)(rowbase + t) * (2 * DI) + DI + d];
            float zsig = 1.f / (1.f + exp2f(-zv * 1.44269504f));
            py[(size_t)(rowbase + t) * DI + d] = packbf((p + Dval * xcv) * (zv * zsig));
        }
    }
}

// ---------------- final FC: (B,512) @ fc_w(256,512)^T + fc_b ----------------
__global__ void fc_kernel(const float* __restrict__ x, const float* __restrict__ fcw,
                          const float* __restrict__ fcb, float* __restrict__ out) {
    int b = blockIdx.x;
    int v = threadIdx.x;   // 0..255
    __shared__ float rep[DM];
    const float* xr = x + (size_t)(b * LSEQ + LSEQ - 1) * DM;
    for (int i = threadIdx.x; i < DM; i += 256) rep[i] = xr[i];
    __syncthreads();
    float acc = fcb[v];
    for (int k = 0; k < DM; k++) acc = fmaf(rep[k], fcw[v * DM + k], acc);
    out[b * VOCABN + v] = acc;
}

extern "C" void kernel_launch(void* const* d_in, const int* in_sizes, int n_in,
                              void* d_out, int out_size, void* d_ws, size_t ws_size,
                              hipStream_t stream) {
    const int*   tokens    = (const int*)  d_in[0];
    const float* emb       = (const float*)d_in[1];
    const float* conv1_w   = (const float*)d_in[2];
    const float* conv1_b   = (const float*)d_in[3];
    const float* ln1_g     = (const float*)d_in[4];
    const float* ln1_b     = (const float*)d_in[5];
    const float* conv2_w   = (const float*)d_in[6];
    const float* conv2_b   = (const float*)d_in[7];
    const float* ln2_g     = (const float*)d_in[8];
    const float* ln2_b     = (const float*)d_in[9];
    const float* pos_emb   = (const float*)d_in[10];
    const float* in_proj_w = (const float*)d_in[11];
    const float* conv_w    = (const float*)d_in[12];
    const float* conv_b    = (const float*)d_in[13];
    const float* x_proj_w  = (const float*)d_in[14];
    const float* dt_proj_w = (const float*)d_in[15];
    const float* dt_proj_b = (const float*)d_in[16];
    const float* A_log     = (const float*)d_in[17];
    const float* Dp_all    = (const float*)d_in[18];
    const float* out_proj_w= (const float*)d_in[19];
    const float* fc_w      = (const float*)d_in[20];
    const float* fc_b      = (const float*)d_in[21];

    float* ws = (float*)d_ws;
    float* X    = ws;                          // (B,L,512) fp32 (fc input)
    float* T1   = X   + 2097152;               // fp32 frontend tmp
    float* XZ   = T1  + 2097152;               // (B,L,2048) fp32
    float* XC   = XZ  + 8388608;               // (B,L,1024) fp32
    float* DT   = XC  + 4194304;               // (B,L,1024) fp32
    uint*  PY   = (uint*)(DT + 4194304);       // (B,L,1024) packed
    float* DBC  = (float*)PY + 4194304;        // (B,L,64) fp32
    uint*  PX   = (uint*)(DBC + 262144);       // (B,L,512) packed
    uint*  PXC  = PX  + 2097152;               // (B,L,1024) packed
    uint*  PWIN = PXC + 4194304;               // 2048x512 packed (per-layer)
    uint*  PWOUT= PWIN + 1048576;              // 512x1024 packed
    uint*  PWX  = PWOUT + 524288;              // 64x1024 packed
    uint*  PWDT = PWX + 65536;                 // 1024x32 packed
    uint*  PDBC = PWDT + 32768;                // (B,L,64) packed
    // aliases (disjoint lifetimes):
    uint*  PX0  = (uint*)XZ;                   // (B,L,384) packed, pre-mamba only
    uint*  PWC1 = (uint*)XC;                   // frontend only
    uint*  PWC2 = (uint*)XC + 983040;          // frontend only
    uint*  PB   = (uint*)DT;                   // frontend only
    // scan chunk states alias PXC (dead after x_proj consumes it): 3 x 1,048,576
    float* SCN_S = (float*)PXC;
    float* SCN_P = SCN_S + 1048576;
    float* SCN_H = SCN_P + 1048576;

    // frontend
    pack_convw_kernel<EMBN, 5><<<(512 * EMBN * 5 + 255) / 256, 256, 0, stream>>>(conv1_w, PWC1);
    pack_convw_kernel<DM,   3><<<(512 * DM   * 3 + 255) / 256, 256, 0, stream>>>(conv2_w, PWC2);
    embed_kernel<<<(MROWS * EMBN) / 256, 256, 0, stream>>>(tokens, emb, PX0);
    conv_mfma_kernel<EMBN, 5, 2><<<dim3(MROWS / 128, 16), 256, 0, stream>>>(PX0, PWC1, conv1_b, T1);
    ln_kernel<false, true><<<MROWS / 4, 256, 0, stream>>>(T1, ln1_g, ln1_b, nullptr, nullptr, PB);
    conv_mfma_kernel<DM, 3, 1><<<dim3(MROWS / 128, 16), 256, 0, stream>>>(PB, PWC2, conv2_b, T1);
    ln_kernel<true, true><<<MROWS / 4, 256, 0, stream>>>(T1, ln2_g, ln2_b, pos_emb, nullptr, PX);

    // mamba layers
    const int NPACK = 2 * DI * DM + DM * DI + 64 * DI + DI * DTRANK;
    for (int l = 0; l < NLAYER; l++) {
        pack4_kernel<<<(NPACK + 255) / 256, 256, 0, stream>>>(
            in_proj_w + (size_t)l * 2 * DI * DM, 2 * DI * DM,
            out_proj_w + (size_t)l * DM * DI, DM * DI,
            x_proj_w + (size_t)l * 64 * DI, 64 * DI,
            dt_proj_w + (size_t)l * DI * DTRANK, DI * DTRANK,
            PWIN, PWOUT, PWX, PWDT);
        gemm_mfma_p<128, 0><<<dim3(MROWS / 128, (2 * DI) / 128), 256, 0, stream>>>(
            PX, DM, PWIN, nullptr, XZ, nullptr, 2 * DI, DM);
        dwconv_silu_kernel<<<(MROWS * DI) / 256, 256, 0, stream>>>(
            XZ, conv_w + (size_t)l * DI * DCONVN, conv_b + (size_t)l * DI, XC, PXC);
        gemm_mfma_p<64, 2><<<dim3(MROWS / 128, 1), 256, 0, stream>>>(
            PXC, DI, PWX, nullptr, DBC, PDBC, 64, DI);
        gemm_mfma_p<128, 3><<<dim3(MROWS / 128, DI / 128), 256, 0, stream>>>(
            PDBC, 64, PWDT, dt_proj_b + (size_t)l * DI, DT, nullptr, DI, DTRANK);
        scan_local_kernel<<<16 * NCHUNK * BBATCH, 256, 0, stream>>>(
            DT, XC, DBC, A_log + (size_t)l * DI * DSTATE, SCN_S, SCN_P);
        scan_combine_kernel<<<(BBATCH * DI * DSTATE) / 256, 256, 0, stream>>>(
            SCN_S, SCN_P, SCN_H);
        scan_out_kernel<<<16 * NCHUNK * BBATCH, 256, 0, stream>>>(
            DT, XC, DBC, XZ, A_log + (size_t)l * DI * DSTATE, Dp_all + (size_t)l * DI,
            SCN_H, PY);
        gemm_mfma_p<64, 2><<<dim3(MROWS / 128, DM / 64), 256, 0, stream>>>(
            PY, DI, PWOUT, nullptr, X, PX, DM, DI);
    }

    fc_kernel<<<BBATCH, 256, 0, stream>>>(X, fc_w, fc_b, (float*)d_out);
}

// Round 8
// 1991.563 us; speedup vs baseline: 1.1551x; 1.1551x over previous
//
#include <hip/hip_runtime.h>
#include <hip/hip_bf16.h>
#include <math.h>

#define VOCABN 256
#define EMBN   384
#define DM     512
#define DI     1024
#define DSTATE 16
#define DCONVN 4
#define DTRANK 32
#define NLAYER 8
#define BBATCH 2
#define LSEQ   2048
#define MROWS  (BBATCH*LSEQ)   // 4096
#define SCHUNK 64
#define NCHUNK (LSEQ/SCHUNK)   // 32

typedef short s8v  __attribute__((ext_vector_type(8)));
typedef float f32x4 __attribute__((ext_vector_type(4)));

// ---------------- bf16 split/pack helpers ----------------
__device__ __forceinline__ ushort f2bf(float f) {
    uint u = __float_as_uint(f);
    return (ushort)((u + 0x7fffu + ((u >> 16) & 1u)) >> 16);
}
__device__ __forceinline__ float bf2f(ushort h) {
    return __uint_as_float((uint)h << 16);
}
// packed element: hi bf16 in high 16 bits, lo bf16 (residual) in low 16 bits
__device__ __forceinline__ uint packbf(float f) {
    ushort h = f2bf(f);
    ushort l = f2bf(f - bf2f(h));
    return ((uint)h << 16) | (uint)l;
}
__device__ __forceinline__ void unp4(uint4 p, ushort* hdst, ushort* ldst) {
    ushort4 h, l;
    h.x = (ushort)(p.x >> 16); l.x = (ushort)(p.x & 0xffffu);
    h.y = (ushort)(p.y >> 16); l.y = (ushort)(p.y & 0xffffu);
    h.z = (ushort)(p.z >> 16); l.z = (ushort)(p.z & 0xffffu);
    h.w = (ushort)(p.w >> 16); l.w = (ushort)(p.w & 0xffffu);
    *(ushort4*)hdst = h; *(ushort4*)ldst = l;
}

// ---------------- pack kernels ----------------
__global__ void pack4_kernel(const float* __restrict__ a, int na,
                             const float* __restrict__ b, int nb,
                             const float* __restrict__ c, int nc,
                             const float* __restrict__ d, int nd,
                             uint* __restrict__ pa, uint* __restrict__ pb,
                             uint* __restrict__ pc, uint* __restrict__ pd) {
    int i = blockIdx.x * 256 + threadIdx.x;
    if (i < na) pa[i] = packbf(a[i]);
    else if (i < na + nb) pb[i - na] = packbf(b[i - na]);
    else if (i < na + nb + nc) pc[i - na - nb] = packbf(c[i - na - nb]);
    else if (i < na + nb + nc + nd) pd[i - na - nb - nc] = packbf(d[i - na - nb - nc]);
}

// conv weights: w[co][ci][k] fp32 -> pw[k][co][ci] packed
template<int CI, int CK>
__global__ void pack_convw_kernel(const float* __restrict__ w, uint* __restrict__ pw) {
    int idx = blockIdx.x * 256 + threadIdx.x;
    if (idx >= 512 * CI * CK) return;
    int k  = idx % CK;
    int ci = (idx / CK) % CI;
    int co = idx / (CK * CI);
    pw[((size_t)(k * 512) + co) * CI + ci] = packbf(w[idx]);
}

// ---------------- embedding gather -> packed ----------------
__global__ void embed_kernel(const int* __restrict__ tok, const float* __restrict__ emb,
                             uint* __restrict__ px0) {
    int idx = blockIdx.x * 256 + threadIdx.x;   // over MROWS*EMBN
    int c = idx % EMBN;
    int t = idx / EMBN;
    px0[idx] = packbf(emb[tok[t] * EMBN + c]);
}

__device__ __forceinline__ float gelu_exact(float x) {
    return 0.5f * x * (1.f + erff(x * 0.70710678118654752f));
}

// ---------------- conv as implicit-GEMM MFMA (bf16x3), 64t x 32co tile ----------------
// 4 waves 2x2: each wave 32t x 16co (MR=2, NR=1)
template<int CI, int CK, int PAD>
__global__ __launch_bounds__(256) void conv_mfma_kernel(
    const uint* __restrict__ PA, const uint* __restrict__ PW,
    const float* __restrict__ bias, float* __restrict__ out)
{
    constexpr int ROWS = 64 + CK - 1;
    const int t0  = blockIdx.x * 64;
    const int co0 = blockIdx.y * 32;
    const int tid = threadIdx.x;
    const int wid = tid >> 6, lane = tid & 63;
    const int rb = (wid >> 1) * 32;
    const int cb = (wid & 1) * 16;
    const int lr = lane & 15, lk = (lane >> 4) * 8;
    const int bstart = (t0 / LSEQ) * LSEQ;

    __shared__ alignas(16) ushort Ah[ROWS][40], Al[ROWS][40];
    __shared__ alignas(16) ushort Bh[CK][32][40], Bl[CK][32][40];

    f32x4 acc[2];
#pragma unroll
    for (int m = 0; m < 2; m++) acc[m] = (f32x4){0.f, 0.f, 0.f, 0.f};

    for (int ci0 = 0; ci0 < CI; ci0 += 32) {
        __syncthreads();
        for (int idx = tid; idx < ROWS * 8; idx += 256) {
            int r = idx >> 3, c4 = (idx & 7) * 4;
            int g = t0 - PAD + r;
            uint4 v = make_uint4(0u, 0u, 0u, 0u);
            if (g >= bstart && g < bstart + LSEQ)
                v = *(const uint4*)&PA[(size_t)g * CI + ci0 + c4];
            unp4(v, &Ah[r][c4], &Al[r][c4]);
        }
        for (int idx = tid; idx < CK * 32 * 8; idx += 256) {
            int k = idx >> 8;
            int r = (idx >> 3) & 31;
            int c4 = (idx & 7) * 4;
            uint4 v = *(const uint4*)&PW[((size_t)(k * 512) + co0 + r) * CI + ci0 + c4];
            unp4(v, &Bh[k][r][c4], &Bl[k][r][c4]);
        }
        __syncthreads();

#pragma unroll
        for (int k = 0; k < CK; k++) {
            s8v ah[2], al[2], bh, bl;
#pragma unroll
            for (int m = 0; m < 2; m++) {
                ah[m] = *(const s8v*)&Ah[rb + m * 16 + lr + k][lk];
                al[m] = *(const s8v*)&Al[rb + m * 16 + lr + k][lk];
            }
            bh = *(const s8v*)&Bh[k][cb + lr][lk];
            bl = *(const s8v*)&Bl[k][cb + lr][lk];
#pragma unroll
            for (int m = 0; m < 2; m++) {
                acc[m] = __builtin_amdgcn_mfma_f32_16x16x32_bf16(ah[m], bh, acc[m], 0, 0, 0);
                acc[m] = __builtin_amdgcn_mfma_f32_16x16x32_bf16(ah[m], bl, acc[m], 0, 0, 0);
                acc[m] = __builtin_amdgcn_mfma_f32_16x16x32_bf16(al[m], bh, acc[m], 0, 0, 0);
            }
        }
    }

    int gcol = co0 + cb + lr;
    float bv = bias[gcol];
#pragma unroll
    for (int m = 0; m < 2; m++) {
#pragma unroll
        for (int r = 0; r < 4; r++) {
            int grow = t0 + rb + m * 16 + (lane >> 4) * 4 + r;
            out[(size_t)grow * 512 + gcol] = gelu_exact(acc[m][r] + bv);
        }
    }
}

// ---------------- layernorm over 512, optional +pos_emb; packed or fp32 out ----------------
template<bool ADDPOS, bool PACK>
__global__ __launch_bounds__(256) void ln_kernel(
    const float* __restrict__ in, const float* __restrict__ g, const float* __restrict__ bb,
    const float* __restrict__ pos, float* __restrict__ out, uint* __restrict__ pout)
{
    int row  = blockIdx.x * 4 + (threadIdx.x >> 6);
    int lane = threadIdx.x & 63;
    const float* xr = in + (size_t)row * DM;
    float v[8];
    float s = 0.f;
#pragma unroll
    for (int i = 0; i < 8; i++) { v[i] = xr[lane + i * 64]; s += v[i]; }
#pragma unroll
    for (int o = 32; o >= 1; o >>= 1) s += __shfl_xor(s, o);
    float mu = s * (1.f / 512.f);
    float var = 0.f;
#pragma unroll
    for (int i = 0; i < 8; i++) { float d = v[i] - mu; var = fmaf(d, d, var); }
#pragma unroll
    for (int o = 32; o >= 1; o >>= 1) var += __shfl_xor(var, o);
    var *= (1.f / 512.f);
    float rstd = rsqrtf(var + 1e-5f);
    int t = row & (LSEQ - 1);
#pragma unroll
    for (int i = 0; i < 8; i++) {
        int c = lane + i * 64;
        float o = (v[i] - mu) * rstd * g[c] + bb[c];
        if (ADDPOS) o += pos[t * DM + c];
        if (PACK) pout[(size_t)row * DM + c] = packbf(o);
        else      out [(size_t)row * DM + c] = o;
    }
}

// ---------------- packed-bf16x3 MFMA GEMM, generic tiling ----------------
// Tile BM x BN, 4 waves in WM x WN grid; per-wave (BM/WM) x (BN/WN) of 16x16 frags.
// EPI: 0 = fp32 C only; 2 = fp32 C + packed PC; 3 = bias+softplus, fp32 C only.
template<int BM, int BN, int WM, int WN, int EPI>
__global__ __launch_bounds__(256) void gemm_mfma_p(
    const uint* __restrict__ PA, int lda,
    const uint* __restrict__ PW,
    const float* __restrict__ bias,
    float* __restrict__ C, uint* __restrict__ PC, int N, int K)
{
    constexpr int MR = BM / WM / 16;
    constexpr int NR = BN / WN / 16;
    constexpr int NLOAD = (BM + BN) * 8 / 256;   // uint4 slots per thread
    const int m0 = blockIdx.x * BM;
    const int n0 = blockIdx.y * BN;
    const int tid = threadIdx.x;
    const int wid = tid >> 6;
    const int lane = tid & 63;
    const int rb = (wid / WN) * (BM / WM);
    const int cb = (wid % WN) * (BN / WN);
    const int lr = lane & 15;
    const int lk = (lane >> 4) * 8;

    __shared__ alignas(16) ushort Ah[BM][40], Al[BM][40];
    __shared__ alignas(16) ushort Bh[BN][40], Bl[BN][40];

    f32x4 acc[MR][NR];
#pragma unroll
    for (int m = 0; m < MR; m++)
#pragma unroll
        for (int n = 0; n < NR; n++) acc[m][n] = (f32x4){0.f, 0.f, 0.f, 0.f};

    for (int k0 = 0; k0 < K; k0 += 32) {
        uint4 v[NLOAD];
#pragma unroll
        for (int i = 0; i < NLOAD; i++) {
            int idx = tid + i * 256;
            int row = idx >> 3, c4 = (idx & 7) * 4;
            v[i] = (row < BM)
                 ? *(const uint4*)&PA[(size_t)(m0 + row) * lda + k0 + c4]
                 : *(const uint4*)&PW[(size_t)(n0 + row - BM) * K + k0 + c4];
        }
        __syncthreads();
#pragma unroll
        for (int i = 0; i < NLOAD; i++) {
            int idx = tid + i * 256;
            int row = idx >> 3, c4 = (idx & 7) * 4;
            if (row < BM) unp4(v[i], &Ah[row][c4], &Al[row][c4]);
            else          unp4(v[i], &Bh[row - BM][c4], &Bl[row - BM][c4]);
        }
        __syncthreads();

        s8v ah[MR], al[MR], bh[NR], bl[NR];
#pragma unroll
        for (int m = 0; m < MR; m++) {
            ah[m] = *(const s8v*)&Ah[rb + m * 16 + lr][lk];
            al[m] = *(const s8v*)&Al[rb + m * 16 + lr][lk];
        }
#pragma unroll
        for (int n = 0; n < NR; n++) {
            bh[n] = *(const s8v*)&Bh[cb + n * 16 + lr][lk];
            bl[n] = *(const s8v*)&Bl[cb + n * 16 + lr][lk];
        }
#pragma unroll
        for (int m = 0; m < MR; m++)
#pragma unroll
            for (int n = 0; n < NR; n++) {
                acc[m][n] = __builtin_amdgcn_mfma_f32_16x16x32_bf16(ah[m], bh[n], acc[m][n], 0, 0, 0);
                acc[m][n] = __builtin_amdgcn_mfma_f32_16x16x32_bf16(ah[m], bl[n], acc[m][n], 0, 0, 0);
                acc[m][n] = __builtin_amdgcn_mfma_f32_16x16x32_bf16(al[m], bh[n], acc[m][n], 0, 0, 0);
            }
    }

    // C/D layout: col = lane&15, row = (lane>>4)*4 + reg
#pragma unroll
    for (int m = 0; m < MR; m++)
#pragma unroll
        for (int n = 0; n < NR; n++) {
#pragma unroll
            for (int r = 0; r < 4; r++) {
                int grow = m0 + rb + m * 16 + (lane >> 4) * 4 + r;
                int gcol = n0 + cb + n * 16 + lr;
                float v = acc[m][n][r];
                if (EPI == 3) {
                    v += bias[gcol];
                    v = fmaxf(v, 0.f) + log1pf(expf(-fabsf(v)));   // softplus, stable
                }
                C[(size_t)grow * N + gcol] = v;
                if (EPI == 2) PC[(size_t)grow * N + gcol] = packbf(v);
            }
        }
}

// ---------------- depthwise causal conv(4) + silu; fp32 + packed out ----------------
__global__ void dwconv_silu_kernel(const float* __restrict__ xz, const float* __restrict__ cw,
                                   const float* __restrict__ cb, float* __restrict__ xc,
                                   uint* __restrict__ pxc) {
    int idx = blockIdx.x * 256 + threadIdx.x;   // over MROWS*DI
    int d = idx & (DI - 1);
    int r = idx >> 10;                          // row = b*L + t
    int tl = r & (LSEQ - 1);
    float acc = cb[d];
#pragma unroll
    for (int k = 0; k < DCONVN; k++) {
        int ts = tl - 3 + k;
        if (ts >= 0) acc = fmaf(xz[(size_t)(r - 3 + k) * (2 * DI) + d], cw[d * DCONVN + k], acc);
    }
    float sig = 1.f / (1.f + expf(-acc));
    float v = acc * sig;
    xc[idx] = v;
    pxc[idx] = packbf(v);
}

// ---------------- chunked selective scan, 4-states-per-thread (round-6 register version) ----------------
__global__ __launch_bounds__(256) void scan_local_kernel(
    const float* __restrict__ dt, const float* __restrict__ xc,
    const float* __restrict__ dbc, const float* __restrict__ A_log,
    float* __restrict__ S, float* __restrict__ P)
{
    const int sg = threadIdx.x & 3;
    const int dl = threadIdx.x >> 2;           // 0..63
    const int dq = blockIdx.x & 15;
    const int c  = (blockIdx.x >> 4) & (NCHUNK - 1);
    const int b  = blockIdx.x >> 9;            // 16*32=512 blocks per batch
    const int d  = dq * 64 + dl;

    float4 alog = *(const float4*)&A_log[d * DSTATE + sg * 4];
    float Av[4]; // -exp(A_log) * log2(e), pre-folded for exp2f
    Av[0] = -expf(alog.x) * 1.44269504f;
    Av[1] = -expf(alog.y) * 1.44269504f;
    Av[2] = -expf(alog.z) * 1.44269504f;
    Av[3] = -expf(alog.w) * 1.44269504f;

    float h[4] = {0.f, 0.f, 0.f, 0.f};
    float sumdt = 0.f;
    const int rowbase = b * LSEQ + c * SCHUNK;

#pragma unroll 4
    for (int t = 0; t < SCHUNK; t++) {
        int r = rowbase + t;
        float dtv = dt[(size_t)r * DI + d];
        float xcv = xc[(size_t)r * DI + d];
        float4 Bv = *(const float4*)&dbc[(size_t)r * 64 + DTRANK + sg * 4];
        float dx = dtv * xcv;
        h[0] = fmaf(exp2f(dtv * Av[0]), h[0], dx * Bv.x);
        h[1] = fmaf(exp2f(dtv * Av[1]), h[1], dx * Bv.y);
        h[2] = fmaf(exp2f(dtv * Av[2]), h[2], dx * Bv.z);
        h[3] = fmaf(exp2f(dtv * Av[3]), h[3], dx * Bv.w);
        sumdt += dtv;
    }
    size_t off = ((size_t)(b * NCHUNK + c) * DI + d) * DSTATE + sg * 4;
    *(float4*)&S[off] = make_float4(h[0], h[1], h[2], h[3]);
    *(float4*)&P[off] = make_float4(exp2f(Av[0] * sumdt), exp2f(Av[1] * sumdt),
                                    exp2f(Av[2] * sumdt), exp2f(Av[3] * sumdt));
}

__global__ __launch_bounds__(256) void scan_combine_kernel(
    const float* __restrict__ S, const float* __restrict__ P, float* __restrict__ H)
{
    int idx = blockIdx.x * 256 + threadIdx.x;    // over B*DI*DSTATE = 32768
    int b = idx >> 14;
    int rem = idx & 16383;                        // d*16+s
    float h = 0.f;
#pragma unroll
    for (int c = 0; c < NCHUNK; c++) {
        size_t off = ((size_t)(b * NCHUNK + c) * DI) * DSTATE + rem;
        H[off] = h;
        h = fmaf(P[off], h, S[off]);
    }
}

__global__ __launch_bounds__(256) void scan_out_kernel(
    const float* __restrict__ dt, const float* __restrict__ xc,
    const float* __restrict__ dbc, const float* __restrict__ xz,
    const float* __restrict__ A_log, const float* __restrict__ Dp,
    const float* __restrict__ H, uint* __restrict__ py)
{
    const int sg = threadIdx.x & 3;
    const int dl = threadIdx.x >> 2;
    const int dq = blockIdx.x & 15;
    const int c  = (blockIdx.x >> 4) & (NCHUNK - 1);
    const int b  = blockIdx.x >> 9;
    const int d  = dq * 64 + dl;

    float4 alog = *(const float4*)&A_log[d * DSTATE + sg * 4];
    float Av[4];
    Av[0] = -expf(alog.x) * 1.44269504f;
    Av[1] = -expf(alog.y) * 1.44269504f;
    Av[2] = -expf(alog.z) * 1.44269504f;
    Av[3] = -expf(alog.w) * 1.44269504f;
    float Dval = Dp[d];

    float4 hv = *(const float4*)&H[((size_t)(b * NCHUNK + c) * DI + d) * DSTATE + sg * 4];
    float h[4] = {hv.x, hv.y, hv.z, hv.w};
    const int rowbase = b * LSEQ + c * SCHUNK;

#pragma unroll 2
    for (int t = 0; t < SCHUNK; t++) {
        int r = rowbase + t;
        float dtv = dt[(size_t)r * DI + d];
        float xcv = xc[(size_t)r * DI + d];
        float4 Bv = *(const float4*)&dbc[(size_t)r * 64 + DTRANK + sg * 4];
        float4 Cv = *(const float4*)&dbc[(size_t)r * 64 + DTRANK + DSTATE + sg * 4];
        float dx = dtv * xcv;
        h[0] = fmaf(exp2f(dtv * Av[0]), h[0], dx * Bv.x);
        h[1] = fmaf(exp2f(dtv * Av[1]), h[1], dx * Bv.y);
        h[2] = fmaf(exp2f(dtv * Av[2]), h[2], dx * Bv.z);
        h[3] = fmaf(exp2f(dtv * Av[3]), h[3], dx * Bv.w);
        float p = h[0] * Cv.x;
        p = fmaf(h[1], Cv.y, p);
        p = fmaf(h[2], Cv.z, p);
        p = fmaf(h[3], Cv.w, p);
        p += __shfl_xor(p, 1);
        p += __shfl_xor(p, 2);
        if (sg == 0) {
            float zv = xz[(size_t)r * (2 * DI) + DI + d];
            float zsig = 1.f / (1.f + exp2f(-zv * 1.44269504f));
            py[(size_t)r * DI + d] = packbf((p + Dval * xcv) * (zv * zsig));
        }
    }
}

// ---------------- final FC: (B,512) @ fc_w(256,512)^T + fc_b ----------------
__global__ void fc_kernel(const float* __restrict__ x, const float* __restrict__ fcw,
                          const float* __restrict__ fcb, float* __restrict__ out) {
    int b = blockIdx.x;
    int v = threadIdx.x;   // 0..255
    __shared__ float rep[DM];
    const float* xr = x + (size_t)(b * LSEQ + LSEQ - 1) * DM;
    for (int i = threadIdx.x; i < DM; i += 256) rep[i] = xr[i];
    __syncthreads();
    float acc = fcb[v];
    for (int k = 0; k < DM; k++) acc = fmaf(rep[k], fcw[v * DM + k], acc);
    out[b * VOCABN + v] = acc;
}

extern "C" void kernel_launch(void* const* d_in, const int* in_sizes, int n_in,
                              void* d_out, int out_size, void* d_ws, size_t ws_size,
                              hipStream_t stream) {
    const int*   tokens    = (const int*)  d_in[0];
    const float* emb       = (const float*)d_in[1];
    const float* conv1_w   = (const float*)d_in[2];
    const float* conv1_b   = (const float*)d_in[3];
    const float* ln1_g     = (const float*)d_in[4];
    const float* ln1_b     = (const float*)d_in[5];
    const float* conv2_w   = (const float*)d_in[6];
    const float* conv2_b   = (const float*)d_in[7];
    const float* ln2_g     = (const float*)d_in[8];
    const float* ln2_b     = (const float*)d_in[9];
    const float* pos_emb   = (const float*)d_in[10];
    const float* in_proj_w = (const float*)d_in[11];
    const float* conv_w    = (const float*)d_in[12];
    const float* conv_b    = (const float*)d_in[13];
    const float* x_proj_w  = (const float*)d_in[14];
    const float* dt_proj_w = (const float*)d_in[15];
    const float* dt_proj_b = (const float*)d_in[16];
    const float* A_log     = (const float*)d_in[17];
    const float* Dp_all    = (const float*)d_in[18];
    const float* out_proj_w= (const float*)d_in[19];
    const float* fc_w      = (const float*)d_in[20];
    const float* fc_b      = (const float*)d_in[21];

    float* ws = (float*)d_ws;
    float* X    = ws;                          // (B,L,512) fp32 (fc input)
    float* T1   = X   + 2097152;               // fp32 frontend tmp
    float* XZ   = T1  + 2097152;               // (B,L,2048) fp32
    float* XC   = XZ  + 8388608;               // (B,L,1024) fp32
    float* DT   = XC  + 4194304;               // (B,L,1024) fp32
    uint*  PY   = (uint*)(DT + 4194304);       // (B,L,1024) packed
    float* DBC  = (float*)PY + 4194304;        // (B,L,64) fp32
    uint*  PX   = (uint*)(DBC + 262144);       // (B,L,512) packed
    uint*  PXC  = PX  + 2097152;               // (B,L,1024) packed
    uint*  PWIN = PXC + 4194304;               // 2048x512 packed (per-layer)
    uint*  PWOUT= PWIN + 1048576;              // 512x1024 packed
    uint*  PWX  = PWOUT + 524288;              // 64x1024 packed
    uint*  PWDT = PWX + 65536;                 // 1024x32 packed
    uint*  PDBC = PWDT + 32768;                // (B,L,64) packed
    // aliases (disjoint lifetimes):
    uint*  PX0  = (uint*)XZ;                   // (B,L,384) packed, pre-mamba only
    uint*  PWC1 = (uint*)XC;                   // frontend only
    uint*  PWC2 = (uint*)XC + 983040;          // frontend only
    uint*  PB   = (uint*)DT;                   // frontend only
    // scan chunk states alias PXC (dead after x_proj consumes it): 3 x 1,048,576
    float* SCN_S = (float*)PXC;
    float* SCN_P = SCN_S + 1048576;
    float* SCN_H = SCN_P + 1048576;

    // frontend
    pack_convw_kernel<EMBN, 5><<<(512 * EMBN * 5 + 255) / 256, 256, 0, stream>>>(conv1_w, PWC1);
    pack_convw_kernel<DM,   3><<<(512 * DM   * 3 + 255) / 256, 256, 0, stream>>>(conv2_w, PWC2);
    embed_kernel<<<(MROWS * EMBN) / 256, 256, 0, stream>>>(tokens, emb, PX0);
    conv_mfma_kernel<EMBN, 5, 2><<<dim3(MROWS / 64, 16), 256, 0, stream>>>(PX0, PWC1, conv1_b, T1);
    ln_kernel<false, true><<<MROWS / 4, 256, 0, stream>>>(T1, ln1_g, ln1_b, nullptr, nullptr, PB);
    conv_mfma_kernel<DM, 3, 1><<<dim3(MROWS / 64, 16), 256, 0, stream>>>(PB, PWC2, conv2_b, T1);
    ln_kernel<true, true><<<MROWS / 4, 256, 0, stream>>>(T1, ln2_g, ln2_b, pos_emb, nullptr, PX);

    // mamba layers
    const int NPACK = 2 * DI * DM + DM * DI + 64 * DI + DI * DTRANK;
    for (int l = 0; l < NLAYER; l++) {
        pack4_kernel<<<(NPACK + 255) / 256, 256, 0, stream>>>(
            in_proj_w + (size_t)l * 2 * DI * DM, 2 * DI * DM,
            out_proj_w + (size_t)l * DM * DI, DM * DI,
            x_proj_w + (size_t)l * 64 * DI, 64 * DI,
            dt_proj_w + (size_t)l * DI * DTRANK, DI * DTRANK,
            PWIN, PWOUT, PWX, PWDT);
        // in_proj: M=4096, N=2048, K=512 -> 64x128 tiles, 1024 blocks
        gemm_mfma_p<64, 128, 1, 4, 0><<<dim3(MROWS / 64, (2 * DI) / 128), 256, 0, stream>>>(
            PX, DM, PWIN, nullptr, XZ, nullptr, 2 * DI, DM);
        dwconv_silu_kernel<<<(MROWS * DI) / 256, 256, 0, stream>>>(
            XZ, conv_w + (size_t)l * DI * DCONVN, conv_b + (size_t)l * DI, XC, PXC);
        // x_proj: M=4096, N=64, K=1024 -> 64x64 tiles, 64 blocks
        gemm_mfma_p<64, 64, 2, 2, 2><<<dim3(MROWS / 64, 1), 256, 0, stream>>>(
            PXC, DI, PWX, nullptr, DBC, PDBC, 64, DI);
        // dt_proj: M=4096, N=1024, K=32 -> 64x64 tiles, 1024 blocks
        gemm_mfma_p<64, 64, 2, 2, 3><<<dim3(MROWS / 64, DI / 64), 256, 0, stream>>>(
            PDBC, 64, PWDT, dt_proj_b + (size_t)l * DI, DT, nullptr, DI, DTRANK);
        scan_local_kernel<<<16 * NCHUNK * BBATCH, 256, 0, stream>>>(
            DT, XC, DBC, A_log + (size_t)l * DI * DSTATE, SCN_S, SCN_P);
        scan_combine_kernel<<<(BBATCH * DI * DSTATE) / 256, 256, 0, stream>>>(
            SCN_S, SCN_P, SCN_H);
        scan_out_kernel<<<16 * NCHUNK * BBATCH, 256, 0, stream>>>(
            DT, XC, DBC, XZ, A_log + (size_t)l * DI * DSTATE, Dp_all + (size_t)l * DI,
            SCN_H, PY);
        // out_proj: M=4096, N=512, K=1024 -> 64x64 tiles, 512 blocks
        gemm_mfma_p<64, 64, 2, 2, 2><<<dim3(MROWS / 64, DM / 64), 256, 0, stream>>>(
            PY, DI, PWOUT, nullptr, X, PX, DM, DI);
    }

    fc_kernel<<<BBATCH, 256, 0, stream>>>(X, fc_w, fc_b, (float*)d_out);
}

// Round 10
// 1868.104 us; speedup vs baseline: 1.2315x; 1.0661x over previous
//
#include <hip/hip_runtime.h>
#include <hip/hip_bf16.h>
#include <math.h>

#define VOCABN 256
#define EMBN   384
#define DM     512
#define DI     1024
#define DSTATE 16
#define DCONVN 4
#define DTRANK 32
#define NLAYER 8
#define BBATCH 2
#define LSEQ   2048
#define MROWS  (BBATCH*LSEQ)   // 4096
#define SCHUNK 32
#define NCHUNK (LSEQ/SCHUNK)   // 64

typedef short s8v  __attribute__((ext_vector_type(8)));
typedef float f32x4 __attribute__((ext_vector_type(4)));

// ---------------- bf16 split/pack helpers ----------------
__device__ __forceinline__ ushort f2bf(float f) {
    uint u = __float_as_uint(f);
    return (ushort)((u + 0x7fffu + ((u >> 16) & 1u)) >> 16);
}
__device__ __forceinline__ float bf2f(ushort h) {
    return __uint_as_float((uint)h << 16);
}
// packed element: hi bf16 in high 16 bits, lo bf16 (residual) in low 16 bits
__device__ __forceinline__ uint packbf(float f) {
    ushort h = f2bf(f);
    ushort l = f2bf(f - bf2f(h));
    return ((uint)h << 16) | (uint)l;
}
__device__ __forceinline__ void unp4(uint4 p, ushort* hdst, ushort* ldst) {
    ushort4 h, l;
    h.x = (ushort)(p.x >> 16); l.x = (ushort)(p.x & 0xffffu);
    h.y = (ushort)(p.y >> 16); l.y = (ushort)(p.y & 0xffffu);
    h.z = (ushort)(p.z >> 16); l.z = (ushort)(p.z & 0xffffu);
    h.w = (ushort)(p.w >> 16); l.w = (ushort)(p.w & 0xffffu);
    *(ushort4*)hdst = h; *(ushort4*)ldst = l;
}

// ---------------- pack kernels ----------------
__global__ void pack4_kernel(const float* __restrict__ a, int na,
                             const float* __restrict__ b, int nb,
                             const float* __restrict__ c, int nc,
                             const float* __restrict__ d, int nd,
                             uint* __restrict__ pa, uint* __restrict__ pb,
                             uint* __restrict__ pc, uint* __restrict__ pd) {
    int i = blockIdx.x * 256 + threadIdx.x;
    if (i < na) pa[i] = packbf(a[i]);
    else if (i < na + nb) pb[i - na] = packbf(b[i - na]);
    else if (i < na + nb + nc) pc[i - na - nb] = packbf(c[i - na - nb]);
    else if (i < na + nb + nc + nd) pd[i - na - nb - nc] = packbf(d[i - na - nb - nc]);
}

// conv weights: w[co][ci][k] fp32 -> pw[k][co][ci] packed
template<int CI, int CK>
__global__ void pack_convw_kernel(const float* __restrict__ w, uint* __restrict__ pw) {
    int idx = blockIdx.x * 256 + threadIdx.x;
    if (idx >= 512 * CI * CK) return;
    int k  = idx % CK;
    int ci = (idx / CK) % CI;
    int co = idx / (CK * CI);
    pw[((size_t)(k * 512) + co) * CI + ci] = packbf(w[idx]);
}

// ---------------- embedding gather -> packed ----------------
__global__ void embed_kernel(const int* __restrict__ tok, const float* __restrict__ emb,
                             uint* __restrict__ px0) {
    int idx = blockIdx.x * 256 + threadIdx.x;   // over MROWS*EMBN
    int c = idx % EMBN;
    int t = idx / EMBN;
    px0[idx] = packbf(emb[tok[t] * EMBN + c]);
}

__device__ __forceinline__ float gelu_exact(float x) {
    return 0.5f * x * (1.f + erff(x * 0.70710678118654752f));
}

// ---------------- conv as implicit-GEMM MFMA (bf16x3), 64t x 32co tile ----------------
// 4 waves 2x2: each wave 32t x 16co (MR=2, NR=1)
template<int CI, int CK, int PAD>
__global__ __launch_bounds__(256) void conv_mfma_kernel(
    const uint* __restrict__ PA, const uint* __restrict__ PW,
    const float* __restrict__ bias, float* __restrict__ out)
{
    constexpr int ROWS = 64 + CK - 1;
    const int t0  = blockIdx.x * 64;
    const int co0 = blockIdx.y * 32;
    const int tid = threadIdx.x;
    const int wid = tid >> 6, lane = tid & 63;
    const int rb = (wid >> 1) * 32;
    const int cb = (wid & 1) * 16;
    const int lr = lane & 15, lk = (lane >> 4) * 8;
    const int bstart = (t0 / LSEQ) * LSEQ;

    __shared__ alignas(16) ushort Ah[ROWS][40], Al[ROWS][40];
    __shared__ alignas(16) ushort Bh[CK][32][40], Bl[CK][32][40];

    f32x4 acc[2];
#pragma unroll
    for (int m = 0; m < 2; m++) acc[m] = (f32x4){0.f, 0.f, 0.f, 0.f};

    for (int ci0 = 0; ci0 < CI; ci0 += 32) {
        __syncthreads();
        for (int idx = tid; idx < ROWS * 8; idx += 256) {
            int r = idx >> 3, c4 = (idx & 7) * 4;
            int g = t0 - PAD + r;
            uint4 v = make_uint4(0u, 0u, 0u, 0u);
            if (g >= bstart && g < bstart + LSEQ)
                v = *(const uint4*)&PA[(size_t)g * CI + ci0 + c4];
            unp4(v, &Ah[r][c4], &Al[r][c4]);
        }
        for (int idx = tid; idx < CK * 32 * 8; idx += 256) {
            int k = idx >> 8;
            int r = (idx >> 3) & 31;
            int c4 = (idx & 7) * 4;
            uint4 v = *(const uint4*)&PW[((size_t)(k * 512) + co0 + r) * CI + ci0 + c4];
            unp4(v, &Bh[k][r][c4], &Bl[k][r][c4]);
        }
        __syncthreads();

#pragma unroll
        for (int k = 0; k < CK; k++) {
            s8v ah[2], al[2], bh, bl;
#pragma unroll
            for (int m = 0; m < 2; m++) {
                ah[m] = *(const s8v*)&Ah[rb + m * 16 + lr + k][lk];
                al[m] = *(const s8v*)&Al[rb + m * 16 + lr + k][lk];
            }
            bh = *(const s8v*)&Bh[k][cb + lr][lk];
            bl = *(const s8v*)&Bl[k][cb + lr][lk];
#pragma unroll
            for (int m = 0; m < 2; m++) {
                acc[m] = __builtin_amdgcn_mfma_f32_16x16x32_bf16(ah[m], bh, acc[m], 0, 0, 0);
                acc[m] = __builtin_amdgcn_mfma_f32_16x16x32_bf16(ah[m], bl, acc[m], 0, 0, 0);
                acc[m] = __builtin_amdgcn_mfma_f32_16x16x32_bf16(al[m], bh, acc[m], 0, 0, 0);
            }
        }
    }

    int gcol = co0 + cb + lr;
    float bv = bias[gcol];
#pragma unroll
    for (int m = 0; m < 2; m++) {
#pragma unroll
        for (int r = 0; r < 4; r++) {
            int grow = t0 + rb + m * 16 + (lane >> 4) * 4 + r;
            out[(size_t)grow * 512 + gcol] = gelu_exact(acc[m][r] + bv);
        }
    }
}

// ---------------- layernorm over 512, optional +pos_emb; packed or fp32 out ----------------
template<bool ADDPOS, bool PACK>
__global__ __launch_bounds__(256) void ln_kernel(
    const float* __restrict__ in, const float* __restrict__ g, const float* __restrict__ bb,
    const float* __restrict__ pos, float* __restrict__ out, uint* __restrict__ pout)
{
    int row  = blockIdx.x * 4 + (threadIdx.x >> 6);
    int lane = threadIdx.x & 63;
    const float* xr = in + (size_t)row * DM;
    float v[8];
    float s = 0.f;
#pragma unroll
    for (int i = 0; i < 8; i++) { v[i] = xr[lane + i * 64]; s += v[i]; }
#pragma unroll
    for (int o = 32; o >= 1; o >>= 1) s += __shfl_xor(s, o);
    float mu = s * (1.f / 512.f);
    float var = 0.f;
#pragma unroll
    for (int i = 0; i < 8; i++) { float d = v[i] - mu; var = fmaf(d, d, var); }
#pragma unroll
    for (int o = 32; o >= 1; o >>= 1) var += __shfl_xor(var, o);
    var *= (1.f / 512.f);
    float rstd = rsqrtf(var + 1e-5f);
    int t = row & (LSEQ - 1);
#pragma unroll
    for (int i = 0; i < 8; i++) {
        int c = lane + i * 64;
        float o = (v[i] - mu) * rstd * g[c] + bb[c];
        if (ADDPOS) o += pos[t * DM + c];
        if (PACK) pout[(size_t)row * DM + c] = packbf(o);
        else      out [(size_t)row * DM + c] = o;
    }
}

// ---------------- packed-bf16x3 MFMA GEMM, generic tiling ----------------
// Tile BM x BN, 4 waves in WM x WN grid; per-wave (BM/WM) x (BN/WN) of 16x16 frags.
// EPI: 0 = fp32 C only; 2 = fp32 C + packed PC; 3 = bias+softplus, fp32 C only.
template<int BM, int BN, int WM, int WN, int EPI>
__global__ __launch_bounds__(256) void gemm_mfma_p(
    const uint* __restrict__ PA, int lda,
    const uint* __restrict__ PW,
    const float* __restrict__ bias,
    float* __restrict__ C, uint* __restrict__ PC, int N, int K)
{
    constexpr int MR = BM / WM / 16;
    constexpr int NR = BN / WN / 16;
    constexpr int NLOAD = (BM + BN) * 8 / 256;   // uint4 slots per thread
    const int m0 = blockIdx.x * BM;
    const int n0 = blockIdx.y * BN;
    const int tid = threadIdx.x;
    const int wid = tid >> 6;
    const int lane = tid & 63;
    const int rb = (wid / WN) * (BM / WM);
    const int cb = (wid % WN) * (BN / WN);
    const int lr = lane & 15;
    const int lk = (lane >> 4) * 8;

    __shared__ alignas(16) ushort Ah[BM][40], Al[BM][40];
    __shared__ alignas(16) ushort Bh[BN][40], Bl[BN][40];

    f32x4 acc[MR][NR];
#pragma unroll
    for (int m = 0; m < MR; m++)
#pragma unroll
        for (int n = 0; n < NR; n++) acc[m][n] = (f32x4){0.f, 0.f, 0.f, 0.f};

    for (int k0 = 0; k0 < K; k0 += 32) {
        uint4 v[NLOAD];
#pragma unroll
        for (int i = 0; i < NLOAD; i++) {
            int idx = tid + i * 256;
            int row = idx >> 3, c4 = (idx & 7) * 4;
            v[i] = (row < BM)
                 ? *(const uint4*)&PA[(size_t)(m0 + row) * lda + k0 + c4]
                 : *(const uint4*)&PW[(size_t)(n0 + row - BM) * K + k0 + c4];
        }
        __syncthreads();
#pragma unroll
        for (int i = 0; i < NLOAD; i++) {
            int idx = tid + i * 256;
            int row = idx >> 3, c4 = (idx & 7) * 4;
            if (row < BM) unp4(v[i], &Ah[row][c4], &Al[row][c4]);
            else          unp4(v[i], &Bh[row - BM][c4], &Bl[row - BM][c4]);
        }
        __syncthreads();

        s8v ah[MR], al[MR], bh[NR], bl[NR];
#pragma unroll
        for (int m = 0; m < MR; m++) {
            ah[m] = *(const s8v*)&Ah[rb + m * 16 + lr][lk];
            al[m] = *(const s8v*)&Al[rb + m * 16 + lr][lk];
        }
#pragma unroll
        for (int n = 0; n < NR; n++) {
            bh[n] = *(const s8v*)&Bh[cb + n * 16 + lr][lk];
            bl[n] = *(const s8v*)&Bl[cb + n * 16 + lr][lk];
        }
#pragma unroll
        for (int m = 0; m < MR; m++)
#pragma unroll
            for (int n = 0; n < NR; n++) {
                acc[m][n] = __builtin_amdgcn_mfma_f32_16x16x32_bf16(ah[m], bh[n], acc[m][n], 0, 0, 0);
                acc[m][n] = __builtin_amdgcn_mfma_f32_16x16x32_bf16(ah[m], bl[n], acc[m][n], 0, 0, 0);
                acc[m][n] = __builtin_amdgcn_mfma_f32_16x16x32_bf16(al[m], bh[n], acc[m][n], 0, 0, 0);
            }
    }

    // C/D layout: col = lane&15, row = (lane>>4)*4 + reg
#pragma unroll
    for (int m = 0; m < MR; m++)
#pragma unroll
        for (int n = 0; n < NR; n++) {
#pragma unroll
            for (int r = 0; r < 4; r++) {
                int grow = m0 + rb + m * 16 + (lane >> 4) * 4 + r;
                int gcol = n0 + cb + n * 16 + lr;
                float v = acc[m][n][r];
                if (EPI == 3) {
                    v += bias[gcol];
                    v = fmaxf(v, 0.f) + log1pf(expf(-fabsf(v)));   // softplus, stable
                }
                C[(size_t)grow * N + gcol] = v;
                if (EPI == 2) PC[(size_t)grow * N + gcol] = packbf(v);
            }
        }
}

// ---------------- depthwise causal conv(4) + silu; fp32 + packed out ----------------
__global__ void dwconv_silu_kernel(const float* __restrict__ xz, const float* __restrict__ cw,
                                   const float* __restrict__ cb, float* __restrict__ xc,
                                   uint* __restrict__ pxc) {
    int idx = blockIdx.x * 256 + threadIdx.x;   // over MROWS*DI
    int d = idx & (DI - 1);
    int r = idx >> 10;                          // row = b*L + t
    int tl = r & (LSEQ - 1);
    float acc = cb[d];
#pragma unroll
    for (int k = 0; k < DCONVN; k++) {
        int ts = tl - 3 + k;
        if (ts >= 0) acc = fmaf(xz[(size_t)(r - 3 + k) * (2 * DI) + d], cw[d * DCONVN + k], acc);
    }
    float sig = 1.f / (1.f + expf(-acc));
    float v = acc * sig;
    xc[idx] = v;
    pxc[idx] = packbf(v);
}

// ---------------- chunked selective scan, 4-states-per-thread ----------------
// thread = (d, sg): sg = tid&3 owns states s = sg*4..sg*4+3 in registers.
// block = 256 thr (64 d x 4 sg). grid = 16 dq x NCHUNK x B = 2048 blocks.
__global__ __launch_bounds__(256) void scan_local_kernel(
    const float* __restrict__ dt, const float* __restrict__ xc,
    const float* __restrict__ dbc, const float* __restrict__ A_log,
    float* __restrict__ S, float* __restrict__ P)
{
    const int sg = threadIdx.x & 3;
    const int dl = threadIdx.x >> 2;           // 0..63
    const int dq = blockIdx.x & 15;
    const int c  = (blockIdx.x >> 4) & (NCHUNK - 1);
    const int b  = blockIdx.x / (16 * NCHUNK);
    const int d  = dq * 64 + dl;

    float4 alog = *(const float4*)&A_log[d * DSTATE + sg * 4];
    float Av[4]; // -exp(A_log) * log2(e), pre-folded for exp2f
    Av[0] = -expf(alog.x) * 1.44269504f;
    Av[1] = -expf(alog.y) * 1.44269504f;
    Av[2] = -expf(alog.z) * 1.44269504f;
    Av[3] = -expf(alog.w) * 1.44269504f;

    float h[4] = {0.f, 0.f, 0.f, 0.f};
    float sumdt = 0.f;
    const int rowbase = b * LSEQ + c * SCHUNK;

#pragma unroll 4
    for (int t = 0; t < SCHUNK; t++) {
        int r = rowbase + t;
        float dtv = dt[(size_t)r * DI + d];
        float xcv = xc[(size_t)r * DI + d];
        float4 Bv = *(const float4*)&dbc[(size_t)r * 64 + DTRANK + sg * 4];
        float dx = dtv * xcv;
        h[0] = fmaf(exp2f(dtv * Av[0]), h[0], dx * Bv.x);
        h[1] = fmaf(exp2f(dtv * Av[1]), h[1], dx * Bv.y);
        h[2] = fmaf(exp2f(dtv * Av[2]), h[2], dx * Bv.z);
        h[3] = fmaf(exp2f(dtv * Av[3]), h[3], dx * Bv.w);
        sumdt += dtv;
    }
    size_t off = ((size_t)(b * NCHUNK + c) * DI + d) * DSTATE + sg * 4;
    *(float4*)&S[off] = make_float4(h[0], h[1], h[2], h[3]);
    *(float4*)&P[off] = make_float4(exp2f(Av[0] * sumdt), exp2f(Av[1] * sumdt),
                                    exp2f(Av[2] * sumdt), exp2f(Av[3] * sumdt));
}

__global__ __launch_bounds__(256) void scan_combine_kernel(
    const float* __restrict__ S, const float* __restrict__ P, float* __restrict__ H)
{
    int idx = blockIdx.x * 256 + threadIdx.x;    // over B*DI*DSTATE = 32768
    int b = idx >> 14;
    int rem = idx & 16383;                        // d*16+s
    float h = 0.f;
#pragma unroll
    for (int c = 0; c < NCHUNK; c++) {
        size_t off = ((size_t)(b * NCHUNK + c) * DI) * DSTATE + rem;
        H[off] = h;
        h = fmaf(P[off], h, S[off]);
    }
}

__global__ __launch_bounds__(256) void scan_out_kernel(
    const float* __restrict__ dt, const float* __restrict__ xc,
    const float* __restrict__ dbc, const float* __restrict__ xz,
    const float* __restrict__ A_log, const float* __restrict__ Dp,
    const float* __restrict__ H, uint* __restrict__ py)
{
    const int sg = threadIdx.x & 3;
    const int dl = threadIdx.x >> 2;
    const int dq = blockIdx.x & 15;
    const int c  = (blockIdx.x >> 4) & (NCHUNK - 1);
    const int b  = blockIdx.x / (16 * NCHUNK);
    const int d  = dq * 64 + dl;

    float4 alog = *(const float4*)&A_log[d * DSTATE + sg * 4];
    float Av[4];
    Av[0] = -expf(alog.x) * 1.44269504f;
    Av[1] = -expf(alog.y) * 1.44269504f;
    Av[2] = -expf(alog.z) * 1.44269504f;
    Av[3] = -expf(alog.w) * 1.44269504f;
    float Dval = Dp[d];

    float4 hv = *(const float4*)&H[((size_t)(b * NCHUNK + c) * DI + d) * DSTATE + sg * 4];
    float h[4] = {hv.x, hv.y, hv.z, hv.w};
    const int rowbase = b * LSEQ + c * SCHUNK;

#pragma unroll 2
    for (int t = 0; t < SCHUNK; t++) {
        int r = rowbase + t;
        float dtv = dt[(size_t)r * DI + d];
        float xcv = xc[(size_t)r * DI + d];
        float4 Bv = *(const float4*)&dbc[(size_t)r * 64 + DTRANK + sg * 4];
        float4 Cv = *(const float4*)&dbc[(size_t)r * 64 + DTRANK + DSTATE + sg * 4];
        float dx = dtv * xcv;
        h[0] = fmaf(exp2f(dtv * Av[0]), h[0], dx * Bv.x);
        h[1] = fmaf(exp2f(dtv * Av[1]), h[1], dx * Bv.y);
        h[2] = fmaf(exp2f(dtv * Av[2]), h[2], dx * Bv.z);
        h[3] = fmaf(exp2f(dtv * Av[3]), h[3], dx * Bv.w);
        float p = h[0] * Cv.x;
        p = fmaf(h[1], Cv.y, p);
        p = fmaf(h[2], Cv.z, p);
        p = fmaf(h[3], Cv.w, p);
        p += __shfl_xor(p, 1);
        p += __shfl_xor(p, 2);
        if (sg == 0) {
            float zv = xz[(size_t)r * (2 * DI) + DI + d];
            float zsig = 1.f / (1.f + exp2f(-zv * 1.44269504f));
            py[(size_t)r * DI + d] = packbf((p + Dval * xcv) * (zv * zsig));
        }
    }
}

// ---------------- final FC: (B,512) @ fc_w(256,512)^T + fc_b ----------------
__global__ void fc_kernel(const float* __restrict__ x, const float* __restrict__ fcw,
                          const float* __restrict__ fcb, float* __restrict__ out) {
    int b = blockIdx.x;
    int v = threadIdx.x;   // 0..255
    __shared__ float rep[DM];
    const float* xr = x + (size_t)(b * LSEQ + LSEQ - 1) * DM;
    for (int i = threadIdx.x; i < DM; i += 256) rep[i] = xr[i];
    __syncthreads();
    float acc = fcb[v];
    for (int k = 0; k < DM; k++) acc = fmaf(rep[k], fcw[v * DM + k], acc);
    out[b * VOCABN + v] = acc;
}

extern "C" void kernel_launch(void* const* d_in, const int* in_sizes, int n_in,
                              void* d_out, int out_size, void* d_ws, size_t ws_size,
                              hipStream_t stream) {
    const int*   tokens    = (const int*)  d_in[0];
    const float* emb       = (const float*)d_in[1];
    const float* conv1_w   = (const float*)d_in[2];
    const float* conv1_b   = (const float*)d_in[3];
    const float* ln1_g     = (const float*)d_in[4];
    const float* ln1_b     = (const float*)d_in[5];
    const float* conv2_w   = (const float*)d_in[6];
    const float* conv2_b   = (const float*)d_in[7];
    const float* ln2_g     = (const float*)d_in[8];
    const float* ln2_b     = (const float*)d_in[9];
    const float* pos_emb   = (const float*)d_in[10];
    const float* in_proj_w = (const float*)d_in[11];
    const float* conv_w    = (const float*)d_in[12];
    const float* conv_b    = (const float*)d_in[13];
    const float* x_proj_w  = (const float*)d_in[14];
    const float* dt_proj_w = (const float*)d_in[15];
    const float* dt_proj_b = (const float*)d_in[16];
    const float* A_log     = (const float*)d_in[17];
    const float* Dp_all    = (const float*)d_in[18];
    const float* out_proj_w= (const float*)d_in[19];
    const float* fc_w      = (const float*)d_in[20];
    const float* fc_b      = (const float*)d_in[21];

    float* ws = (float*)d_ws;
    float* X    = ws;                          // (B,L,512) fp32 (fc input)
    float* T1   = X   + 2097152;               // fp32 frontend tmp; then SCN_S
    float* XZ   = T1  + 2097152;               // (B,L,2048) fp32
    float* XC   = XZ  + 8388608;               // (B,L,1024) fp32
    float* DT   = XC  + 4194304;               // (B,L,1024) fp32
    uint*  PY   = (uint*)(DT + 4194304);       // (B,L,1024) packed
    float* DBC  = (float*)PY + 4194304;        // (B,L,64) fp32
    uint*  PX   = (uint*)(DBC + 262144);       // (B,L,512) packed
    uint*  PXC  = PX  + 2097152;               // (B,L,1024) packed
    uint*  PWIN = PXC + 4194304;               // 2048x512 packed (per-layer)
    uint*  PWOUT= PWIN + 1048576;              // 512x1024 packed
    uint*  PWX  = PWOUT + 524288;              // 64x1024 packed
    uint*  PWDT = PWX + 65536;                 // 1024x32 packed
    uint*  PDBC = PWDT + 32768;                // (B,L,64) packed
    // aliases (disjoint lifetimes):
    uint*  PX0  = (uint*)XZ;                   // (B,L,384) packed, pre-mamba only
    uint*  PWC1 = (uint*)XC;                   // frontend only
    uint*  PWC2 = (uint*)XC + 983040;          // frontend only
    uint*  PB   = (uint*)DT;                   // frontend only
    // scan chunk states (NCHUNK=64): 3 x 2,097,152 floats.
    // S aliases T1 (frontend-dead); P,H alias PXC (dead after x_proj consumes it).
    float* SCN_S = T1;
    float* SCN_P = (float*)PXC;
    float* SCN_H = (float*)PXC + 2097152;

    // frontend
    pack_convw_kernel<EMBN, 5><<<(512 * EMBN * 5 + 255) / 256, 256, 0, stream>>>(conv1_w, PWC1);
    pack_convw_kernel<DM,   3><<<(512 * DM   * 3 + 255) / 256, 256, 0, stream>>>(conv2_w, PWC2);
    embed_kernel<<<(MROWS * EMBN) / 256, 256, 0, stream>>>(tokens, emb, PX0);
    conv_mfma_kernel<EMBN, 5, 2><<<dim3(MROWS / 64, 16), 256, 0, stream>>>(PX0, PWC1, conv1_b, T1);
    ln_kernel<false, true><<<MROWS / 4, 256, 0, stream>>>(T1, ln1_g, ln1_b, nullptr, nullptr, PB);
    conv_mfma_kernel<DM, 3, 1><<<dim3(MROWS / 64, 16), 256, 0, stream>>>(PB, PWC2, conv2_b, T1);
    ln_kernel<true, true><<<MROWS / 4, 256, 0, stream>>>(T1, ln2_g, ln2_b, pos_emb, nullptr, PX);

    // mamba layers
    const int NPACK = 2 * DI * DM + DM * DI + 64 * DI + DI * DTRANK;
    for (int l = 0; l < NLAYER; l++) {
        pack4_kernel<<<(NPACK + 255) / 256, 256, 0, stream>>>(
            in_proj_w + (size_t)l * 2 * DI * DM, 2 * DI * DM,
            out_proj_w + (size_t)l * DM * DI, DM * DI,
            x_proj_w + (size_t)l * 64 * DI, 64 * DI,
            dt_proj_w + (size_t)l * DI * DTRANK, DI * DTRANK,
            PWIN, PWOUT, PWX, PWDT);
        // in_proj: M=4096, N=2048, K=512 -> 64x128 tiles, 1024 blocks
        gemm_mfma_p<64, 128, 1, 4, 0><<<dim3(MROWS / 64, (2 * DI) / 128), 256, 0, stream>>>(
            PX, DM, PWIN, nullptr, XZ, nullptr, 2 * DI, DM);
        dwconv_silu_kernel<<<(MROWS * DI) / 256, 256, 0, stream>>>(
            XZ, conv_w + (size_t)l * DI * DCONVN, conv_b + (size_t)l * DI, XC, PXC);
        // x_proj: M=4096, N=64, K=1024 -> 64x64 tiles, 64 blocks
        gemm_mfma_p<64, 64, 2, 2, 2><<<dim3(MROWS / 64, 1), 256, 0, stream>>>(
            PXC, DI, PWX, nullptr, DBC, PDBC, 64, DI);
        // dt_proj: M=4096, N=1024, K=32 -> 64x64 tiles, 1024 blocks
        gemm_mfma_p<64, 64, 2, 2, 3><<<dim3(MROWS / 64, DI / 64), 256, 0, stream>>>(
            PDBC, 64, PWDT, dt_proj_b + (size_t)l * DI, DT, nullptr, DI, DTRANK);
        scan_local_kernel<<<16 * NCHUNK * BBATCH, 256, 0, stream>>>(
            DT, XC, DBC, A_log + (size_t)l * DI * DSTATE, SCN_S, SCN_P);
        scan_combine_kernel<<<(BBATCH * DI * DSTATE) / 256, 256, 0, stream>>>(
            SCN_S, SCN_P, SCN_H);
        scan_out_kernel<<<16 * NCHUNK * BBATCH, 256, 0, stream>>>(
            DT, XC, DBC, XZ, A_log + (size_t)l * DI * DSTATE, Dp_all + (size_t)l * DI,
            SCN_H, PY);
        // out_proj: M=4096, N=512, K=1024 -> 64x64 tiles, 512 blocks
        gemm_mfma_p<64, 64, 2, 2, 2><<<dim3(MROWS / 64, DM / 64), 256, 0, stream>>>(
            PY, DI, PWOUT, nullptr, X, PX, DM, DI);
    }

    fc_kernel<<<BBATCH, 256, 0, stream>>>(X, fc_w, fc_b, (float*)d_out);
}